// Round 7
// baseline (493.774 us; speedup 1.0000x reference)
//
#include <hip/hip_runtime.h>
#include <hip/hip_bf16.h>
#include <hip/hip_cooperative_groups.h>
#include <stdint.h>

namespace cg = cooperative_groups;

// 2-layer GCN + global mean pool + MLP head. N=100000, E=1600000, G=512. fp32.
//
// Fully scalarized (see round-6): per-edge state is scalar, so the whole GNN
// reduces to 3 scalar segment-sums per node over dst-bucket-grouped edges:
//   xd = x*dinv;  t[d] = dinv[d]*(sum xd[src] + xd[d]);  uv = (dinv*t, dinv)
//   (T,D,A)[d] = sum (u_s, v_s, |u_s|) + self;  abc = (dinv/2)*(T,D,A)
//   h2[d,j] = relu(a*alpha_j + b*beta_j + c*gamma_j + b2_j)   (rank-3, b1==0 ok:
//   beta folds b1 through W2 so it is exact for any b1)
//
// Round-7 changes:
//  - CHUNK 16384->4096: k_scatter/k_hist get 391 blocks (was 98) — scatter was
//    request-throughput-bound on 98 CUs (44 us).
//  - k_degxd/k_t/k_tda fused into ONE cooperative kernel (grid.sync between
//    phases): ebuf slice read once (L1-hot), 2 launches + 2 HBM re-reads saved.
//  - k_abg folded into k_poolhead prologue. 9 launches -> 6.

#define CHUNK   4096
#define MAXBUCK 1600

static inline size_t align_up(size_t x, size_t a){ return (x + a - 1) & ~(a - 1); }

// --- Pass A: per-chunk bucket histogram (LDS) ---
__global__ void __launch_bounds__(256) k_hist(const int* __restrict__ dst,
                                              int* __restrict__ hist, int E, int nbuck){
    __shared__ int h[MAXBUCK];
    for (int i = threadIdx.x; i < nbuck; i += 256) h[i] = 0;
    __syncthreads();
    int base = blockIdx.x * CHUNK;
    int end = min(base + CHUNK, E);
    for (int i = base + threadIdx.x; i < end; i += 256)
        atomicAdd(&h[dst[i] >> 6], 1);
    __syncthreads();
    int* row = hist + (size_t)blockIdx.x * nbuck;
    for (int i = threadIdx.x; i < nbuck; i += 256) row[i] = h[i];
}

// --- Pass B1: per-bucket running offset across chunks; bucket totals ---
__global__ void k_cscanA(int* __restrict__ hist, int* __restrict__ btot,
                         int nch, int nbuck){
    int b = blockIdx.x * 256 + threadIdx.x;
    if (b >= nbuck) return;
    int run = 0;
    #pragma unroll 4
    for (int c = 0; c < nch; ++c){
        int* p = hist + (size_t)c * nbuck + b;
        int t = *p;
        *p = run;
        run += t;
    }
    btot[b] = run;
}

// --- Pass B2: exclusive scan of bucket totals -> bucket base offsets ---
__global__ void k_cscanB(const int* __restrict__ btot, int* __restrict__ babs,
                         int nbuck, int E){
    __shared__ int sh[256];
    int t = threadIdx.x;
    int it = (nbuck + 255) / 256;  // <= 16
    int v[16];
    int sum = 0;
    int base = t * it;
    for (int u = 0; u < it; ++u){
        int idx = base + u;
        v[u] = (idx < nbuck) ? btot[idx] : 0;
        sum += v[u];
    }
    sh[t] = sum; __syncthreads();
    for (int off = 1; off < 256; off <<= 1){
        int xv = (t >= off) ? sh[t - off] : 0;
        __syncthreads();
        if (t >= off) sh[t] += xv;
        __syncthreads();
    }
    int run = (t == 0) ? 0 : sh[t - 1];
    for (int u = 0; u < it; ++u){
        int idx = base + u;
        if (idx < nbuck) babs[idx] = run;
        run += v[u];
    }
    if (t == 0) babs[nbuck] = E;
}

// --- Pass C: ordered scatter into bucket-grouped packed ebuf (LDS cursors) ---
__global__ void __launch_bounds__(256) k_scatter(
        const int* __restrict__ src, const int* __restrict__ dst,
        const int* __restrict__ hist, const int* __restrict__ babs,
        int* __restrict__ ebuf, int E, int nbuck){
    __shared__ int lcur[MAXBUCK];
    const int* rel = hist + (size_t)blockIdx.x * nbuck;
    for (int i = threadIdx.x; i < nbuck; i += 256) lcur[i] = babs[i] + rel[i];
    __syncthreads();
    int base = blockIdx.x * CHUNK;
    int end = min(base + CHUNK, E);
    for (int i = base + threadIdx.x; i < end; i += 256){
        int s = src[i], d = dst[i];
        int slot = atomicAdd(&lcur[d >> 6], 1);
        ebuf[slot] = (s << 6) | (d & 63);
    }
}

// --- fused node pipeline: deg/dinv/xd -> t/uv -> TDA/abc (cooperative) ---
// grid = NBUCK blocks x 256 threads; 4 waves/block, <=64 VGPR -> co-resident.
__global__ void __launch_bounds__(256, 8) k_nodes(
        const int* __restrict__ ebuf, const int* __restrict__ babs,
        const float* __restrict__ x, float* __restrict__ xd,
        float2* __restrict__ uv, float4* __restrict__ abc, int N){
    cg::grid_group grid = cg::this_grid();
    __shared__ int cnt[64];
    __shared__ float A0[64], A1[64], A2[64], dl[64];
    int b = blockIdx.x, node0 = b << 6, t = threadIdx.x;
    int beg = babs[b], end = babs[b + 1];

    // phase 1: degree -> dinv (LDS), xd = x*dinv (global)
    if (t < 64) cnt[t] = 0;
    __syncthreads();
    for (int i = beg + t; i < end; i += 256)
        atomicAdd(&cnt[ebuf[i] & 63], 1);
    __syncthreads();
    if (t < 64){
        float di = rsqrtf((float)cnt[t] + 1.0f);
        dl[t] = di;
        int n = node0 + t;
        if (n < N) xd[n] = x[n] * di;
    }
    grid.sync();

    // phase 2: t[d] = dinv*(sum xd[src] + xd[d]); uv = (dinv*t, dinv)
    if (t < 64) A0[t] = 0.f;
    __syncthreads();
    for (int i = beg + t; i < end; i += 256){
        int e = ebuf[i];
        atomicAdd(&A0[e & 63], xd[e >> 6]);
    }
    __syncthreads();
    if (t < 64){
        int n = node0 + t;
        if (n < N){
            float di = dl[t];
            float tv = di * (A0[t] + xd[n]);
            uv[n] = make_float2(di * tv, di);
        }
    }
    grid.sync();

    // phase 3: (T,D,A) sums; abc = (dinv/2)*(T,D,A) incl. self term
    if (t < 64){ A0[t] = 0.f; A1[t] = 0.f; A2[t] = 0.f; }
    __syncthreads();
    for (int i = beg + t; i < end; i += 256){
        int e = ebuf[i];
        float2 s = uv[e >> 6];
        int j = e & 63;
        atomicAdd(&A0[j], s.x);
        atomicAdd(&A1[j], s.y);
        atomicAdd(&A2[j], fabsf(s.x));
    }
    __syncthreads();
    if (t < 64){
        int n = node0 + t;
        if (n < N){
            float2 s = uv[n];
            float hd = 0.5f * dl[t];
            abc[n] = make_float4(hd * (A0[t] + s.x), hd * (A1[t] + s.y),
                                 hd * (A2[t] + fabsf(s.x)), 0.f);
        }
    }
}

// --- fused: abg fold + rank-3 relu -> mean pool -> MLP head. Block per graph. ---
#define NS 32
__global__ void __launch_bounds__(128) k_poolhead(
        const float4* __restrict__ abc, const int* __restrict__ batch,
        const float* __restrict__ W1, const float* __restrict__ b1,
        const float* __restrict__ W2, const float* __restrict__ b2,
        const float* __restrict__ Wl1, const float* __restrict__ bl1,
        const float* __restrict__ Wl2, const float* __restrict__ bl2,
        float* __restrict__ out, int N){
    __shared__ float4 st[NS];
    __shared__ float pooled[128];
    __shared__ float h3s[64];
    int g = blockIdx.x;
    int t = threadIdx.x;  // 128
    // fold W1/b1 through W2: alpha/beta/gamma for this thread's column
    float al = 0.f, be = 0.f, ga = 0.f;
    #pragma unroll
    for (int c = 0; c < 64; ++c){
        float w2 = W2[c * 128 + t];
        al = fmaf(W1[c], w2, al);
        be = fmaf(b1[c], w2, be);
        ga = fmaf(fabsf(W1[c]), w2, ga);
    }
    float b2j = b2[t];
    int lo = 0, hi = N;
    while (lo < hi){ int m = (lo + hi) >> 1; if (batch[m] < g) lo = m + 1; else hi = m; }
    int lo2 = lo, hi2 = N;
    while (lo2 < hi2){ int m = (lo2 + hi2) >> 1; if (batch[m] < g + 1) lo2 = m + 1; else hi2 = m; }
    int cnt = lo2 - lo;
    float pool = 0.f;
    for (int base = lo; base < lo2; base += NS){
        int ns = min(NS, lo2 - base);
        if (t < 4 * ns) ((float*)st)[t] = ((const float*)(abc + base))[t];
        __syncthreads();
        for (int u = 0; u < ns; ++u){
            float4 s = st[u];
            float h = fmaf(s.x, al, fmaf(s.y, be, fmaf(s.z, ga, b2j)));
            pool += fmaxf(h, 0.f);
        }
        __syncthreads();
    }
    pooled[t] = pool / (float)(cnt > 0 ? cnt : 1);
    __syncthreads();
    if (t < 64){
        float a = bl1[t];
        #pragma unroll
        for (int k = 0; k < 128; ++k) a = fmaf(pooled[k], Wl1[k * 64 + t], a);
        h3s[t] = fmaxf(a, 0.f);
    }
    __syncthreads();
    if (t < 4){
        float o = bl2[t];
        #pragma unroll
        for (int j = 0; j < 64; ++j) o = fmaf(h3s[j], Wl2[j * 4 + t], o);
        out[g * 4 + t] = o;
    }
}

extern "C" void kernel_launch(void* const* d_in, const int* in_sizes, int n_in,
                              void* d_out, int out_size, void* d_ws, size_t ws_size,
                              hipStream_t stream) {
    const float* x    = (const float*)d_in[0];
    const int*   ei   = (const int*)d_in[1];
    const int*   batch= (const int*)d_in[2];
    const float* W1   = (const float*)d_in[3];
    const float* b1   = (const float*)d_in[4];
    const float* W2   = (const float*)d_in[5];
    const float* b2   = (const float*)d_in[6];
    const float* Wl1  = (const float*)d_in[7];
    const float* bl1  = (const float*)d_in[8];
    const float* Wl2  = (const float*)d_in[9];
    const float* bl2  = (const float*)d_in[10];

    const int N = in_sizes[0];
    const int E = in_sizes[1] / 2;
    const int G = out_size / 4;
    const int* srcp = ei;
    const int* dstp = ei + E;
    const int NBUCK = (N + 63) >> 6;            // 1563
    const int NCH   = (E + CHUNK - 1) / CHUNK;  // 391

    // Workspace (re-poisoned each call; every buffer fully written before read).
    char* p = (char*)d_ws;
    size_t off = 0;
    int*    hist = (int*)(p + off);    off += align_up((size_t)NCH * NBUCK * 4, 16);
    int*    btot = (int*)(p + off);    off += align_up((size_t)NBUCK * 4, 16);
    int*    babs = (int*)(p + off);    off += align_up((size_t)(NBUCK + 1) * 4, 16);
    float*  xd   = (float*)(p + off);  off += align_up((size_t)N * 4, 16);
    float2* uv   = (float2*)(p + off); off += align_up((size_t)N * 8, 16);
    float4* abc  = (float4*)(p + off); off += align_up((size_t)N * 16, 16);
    int*    ebuf = (int*)(p + off);    off += align_up((size_t)E * 4, 16);
    (void)ws_size; (void)n_in;

    k_hist   <<<NCH, 256, 0, stream>>>(dstp, hist, E, NBUCK);
    k_cscanA <<<(NBUCK + 255) / 256, 256, 0, stream>>>(hist, btot, NCH, NBUCK);
    k_cscanB <<<1, 256, 0, stream>>>(btot, babs, NBUCK, E);
    k_scatter<<<NCH, 256, 0, stream>>>(srcp, dstp, hist, babs, ebuf, E, NBUCK);

    {   // cooperative: fused deg/dinv/xd -> uv -> abc with grid-wide syncs
        void* args[] = { (void*)&ebuf, (void*)&babs, (void*)&x, (void*)&xd,
                         (void*)&uv, (void*)&abc, (void*)&N };
        hipLaunchCooperativeKernel((const void*)k_nodes, dim3(NBUCK), dim3(256),
                                   args, 0, stream);
    }

    k_poolhead<<<G, 128, 0, stream>>>(abc, batch, W1, b1, W2, b2,
                                      Wl1, bl1, Wl2, bl2, (float*)d_out, N);
}

// Round 8
// 233.770 us; speedup vs baseline: 2.1122x; 2.1122x over previous
//
#include <hip/hip_runtime.h>
#include <hip/hip_bf16.h>
#include <stdint.h>

// 2-layer GCN + global mean pool + MLP head. N=100000, E=1600000, G=512. fp32.
//
// Fully scalarized: per-edge state is scalar, so the whole GNN reduces to 3
// scalar segment-sums per node over dst-bucket-grouped edges:
//   xd = x*dinv;  t[d] = dinv[d]*(sum xd[src] + xd[d]);  uv = (dinv*t, dinv)
//   (T,D,A)[d] = sum (u_s, v_s, |u_s|) + self;  abc = (dinv/2)*(T,D,A)
//   h2[d,j] = relu(a*alpha_j + b*beta_j + c*gamma_j + b2_j)
//   alpha/beta/gamma fold W1/b1 through W2 (exact for any b1).
//
// Round-7 lesson: cooperative grid.sync across 1563 blocks cost ~100 us per
// barrier (spin-wait + slowest-bucket gating) — separate kernel launches are
// cheaper. Reverted to round-6 structure; kept CHUNK=4096 (391-block scatter,
// was request-throughput-bound on 98 CUs) and the abg fold into k_poolhead.

#define CHUNK   4096
#define MAXBUCK 1600

static inline size_t align_up(size_t x, size_t a){ return (x + a - 1) & ~(a - 1); }

// --- Pass A: per-chunk bucket histogram (LDS) ---
__global__ void __launch_bounds__(256) k_hist(const int* __restrict__ dst,
                                              int* __restrict__ hist, int E, int nbuck){
    __shared__ int h[MAXBUCK];
    for (int i = threadIdx.x; i < nbuck; i += 256) h[i] = 0;
    __syncthreads();
    int base = blockIdx.x * CHUNK;
    int end = min(base + CHUNK, E);
    for (int i = base + threadIdx.x; i < end; i += 256)
        atomicAdd(&h[dst[i] >> 6], 1);
    __syncthreads();
    int* row = hist + (size_t)blockIdx.x * nbuck;
    for (int i = threadIdx.x; i < nbuck; i += 256) row[i] = h[i];
}

// --- Pass B1: per-bucket running offset across chunks; bucket totals ---
__global__ void k_cscanA(int* __restrict__ hist, int* __restrict__ btot,
                         int nch, int nbuck){
    int b = blockIdx.x * 256 + threadIdx.x;
    if (b >= nbuck) return;
    int run = 0;
    #pragma unroll 4
    for (int c = 0; c < nch; ++c){
        int* p = hist + (size_t)c * nbuck + b;
        int t = *p;
        *p = run;
        run += t;
    }
    btot[b] = run;
}

// --- Pass B2: exclusive scan of bucket totals -> bucket base offsets ---
__global__ void k_cscanB(const int* __restrict__ btot, int* __restrict__ babs,
                         int nbuck, int E){
    __shared__ int sh[256];
    int t = threadIdx.x;
    int it = (nbuck + 255) / 256;  // <= 16
    int v[16];
    int sum = 0;
    int base = t * it;
    for (int u = 0; u < it; ++u){
        int idx = base + u;
        v[u] = (idx < nbuck) ? btot[idx] : 0;
        sum += v[u];
    }
    sh[t] = sum; __syncthreads();
    for (int off = 1; off < 256; off <<= 1){
        int xv = (t >= off) ? sh[t - off] : 0;
        __syncthreads();
        if (t >= off) sh[t] += xv;
        __syncthreads();
    }
    int run = (t == 0) ? 0 : sh[t - 1];
    for (int u = 0; u < it; ++u){
        int idx = base + u;
        if (idx < nbuck) babs[idx] = run;
        run += v[u];
    }
    if (t == 0) babs[nbuck] = E;
}

// --- Pass C: ordered scatter into bucket-grouped packed ebuf (LDS cursors) ---
__global__ void __launch_bounds__(256) k_scatter(
        const int* __restrict__ src, const int* __restrict__ dst,
        const int* __restrict__ hist, const int* __restrict__ babs,
        int* __restrict__ ebuf, int E, int nbuck){
    __shared__ int lcur[MAXBUCK];
    const int* rel = hist + (size_t)blockIdx.x * nbuck;
    for (int i = threadIdx.x; i < nbuck; i += 256) lcur[i] = babs[i] + rel[i];
    __syncthreads();
    int base = blockIdx.x * CHUNK;
    int end = min(base + CHUNK, E);
    for (int i = base + threadIdx.x; i < end; i += 256){
        int s = src[i], d = dst[i];
        int slot = atomicAdd(&lcur[d >> 6], 1);
        ebuf[slot] = (s << 6) | (d & 63);
    }
}

// --- degree -> dinv, xd = x*dinv (per bucket, LDS counters) ---
__global__ void __launch_bounds__(256) k_degxd(
        const int* __restrict__ ebuf, const int* __restrict__ babs,
        const float* __restrict__ x, float* __restrict__ dinv,
        float* __restrict__ xd, int N){
    __shared__ int cnt[64];
    int b = blockIdx.x, node0 = b << 6, t = threadIdx.x;
    if (t < 64) cnt[t] = 0;
    __syncthreads();
    int beg = babs[b], end = babs[b + 1];
    for (int i = beg + t; i < end; i += 256)
        atomicAdd(&cnt[ebuf[i] & 63], 1);
    __syncthreads();
    if (t < 64 && node0 + t < N){
        float di = rsqrtf((float)cnt[t] + 1.0f);
        dinv[node0 + t] = di;
        xd[node0 + t] = x[node0 + t] * di;
    }
}

// --- layer-1 scalar t per node; write uv = (dinv*t, dinv) ---
__global__ void __launch_bounds__(256) k_t(
        const int* __restrict__ ebuf, const int* __restrict__ babs,
        const float* __restrict__ xd, const float* __restrict__ dinv,
        float2* __restrict__ uv, int N){
    __shared__ float tl[64], dl[64];
    int b = blockIdx.x, node0 = b << 6, t = threadIdx.x;
    if (t < 64){
        tl[t] = 0.f;
        int n = node0 + t;
        dl[t] = (n < N) ? dinv[n] : 0.f;
    }
    __syncthreads();
    int beg = babs[b], end = babs[b + 1];
    for (int i = beg + t; i < end; i += 256){
        int e = ebuf[i];
        atomicAdd(&tl[e & 63], xd[e >> 6]);
    }
    __syncthreads();
    if (t < 64 && node0 + t < N){
        int n = node0 + t;
        float tv = dl[t] * (tl[t] + xd[n]);
        uv[n] = make_float2(dl[t] * tv, dl[t]);
    }
}

// --- layer-2 scalar sums (T,D,A) per node; write abc = (dinv/2)*(T,D,A) ---
__global__ void __launch_bounds__(256) k_tda(
        const int* __restrict__ ebuf, const int* __restrict__ babs,
        const float2* __restrict__ uv, float4* __restrict__ abc, int N){
    __shared__ float TL[64], DL[64], AL[64], dl2[64];
    int b = blockIdx.x, node0 = b << 6, t = threadIdx.x;
    if (t < 64){
        TL[t] = 0.f; DL[t] = 0.f; AL[t] = 0.f;
        int n = node0 + t;
        dl2[t] = (n < N) ? uv[n].y : 0.f;   // dinv
    }
    __syncthreads();
    int beg = babs[b], end = babs[b + 1];
    for (int i = beg + t; i < end; i += 256){
        int e = ebuf[i];
        float2 s = uv[e >> 6];
        int j = e & 63;
        atomicAdd(&TL[j], s.x);
        atomicAdd(&DL[j], s.y);
        atomicAdd(&AL[j], fabsf(s.x));
    }
    __syncthreads();
    if (t < 64 && node0 + t < N){
        int n = node0 + t;
        float2 s = uv[n];                    // self-loop contribution
        float half_d = 0.5f * dl2[t];
        float T = TL[t] + s.x;
        float D = DL[t] + s.y;
        float A = AL[t] + fabsf(s.x);
        abc[n] = make_float4(half_d * T, half_d * D, half_d * A, 0.f);
    }
}

// --- fused: abg fold + rank-3 relu -> mean pool -> MLP head. Block per graph. ---
#define NS 32
__global__ void __launch_bounds__(128) k_poolhead(
        const float4* __restrict__ abc, const int* __restrict__ batch,
        const float* __restrict__ W1, const float* __restrict__ b1,
        const float* __restrict__ W2, const float* __restrict__ b2,
        const float* __restrict__ Wl1, const float* __restrict__ bl1,
        const float* __restrict__ Wl2, const float* __restrict__ bl2,
        float* __restrict__ out, int N){
    __shared__ float4 st[NS];
    __shared__ float pooled[128];
    __shared__ float h3s[64];
    int g = blockIdx.x;
    int t = threadIdx.x;  // 128
    // fold W1/b1 through W2: alpha/beta/gamma for this thread's column
    float al = 0.f, be = 0.f, ga = 0.f;
    #pragma unroll
    for (int c = 0; c < 64; ++c){
        float w2 = W2[c * 128 + t];
        al = fmaf(W1[c], w2, al);
        be = fmaf(b1[c], w2, be);
        ga = fmaf(fabsf(W1[c]), w2, ga);
    }
    float b2j = b2[t];
    int lo = 0, hi = N;
    while (lo < hi){ int m = (lo + hi) >> 1; if (batch[m] < g) lo = m + 1; else hi = m; }
    int lo2 = lo, hi2 = N;
    while (lo2 < hi2){ int m = (lo2 + hi2) >> 1; if (batch[m] < g + 1) lo2 = m + 1; else hi2 = m; }
    int cnt = lo2 - lo;
    float pool = 0.f;
    for (int base = lo; base < lo2; base += NS){
        int ns = min(NS, lo2 - base);
        if (t < 4 * ns) ((float*)st)[t] = ((const float*)(abc + base))[t];
        __syncthreads();
        for (int u = 0; u < ns; ++u){
            float4 s = st[u];
            float h = fmaf(s.x, al, fmaf(s.y, be, fmaf(s.z, ga, b2j)));
            pool += fmaxf(h, 0.f);
        }
        __syncthreads();
    }
    pooled[t] = pool / (float)(cnt > 0 ? cnt : 1);
    __syncthreads();
    if (t < 64){
        float a = bl1[t];
        #pragma unroll
        for (int k = 0; k < 128; ++k) a = fmaf(pooled[k], Wl1[k * 64 + t], a);
        h3s[t] = fmaxf(a, 0.f);
    }
    __syncthreads();
    if (t < 4){
        float o = bl2[t];
        #pragma unroll
        for (int j = 0; j < 64; ++j) o = fmaf(h3s[j], Wl2[j * 4 + t], o);
        out[g * 4 + t] = o;
    }
}

extern "C" void kernel_launch(void* const* d_in, const int* in_sizes, int n_in,
                              void* d_out, int out_size, void* d_ws, size_t ws_size,
                              hipStream_t stream) {
    const float* x    = (const float*)d_in[0];
    const int*   ei   = (const int*)d_in[1];
    const int*   batch= (const int*)d_in[2];
    const float* W1   = (const float*)d_in[3];
    const float* b1   = (const float*)d_in[4];
    const float* W2   = (const float*)d_in[5];
    const float* b2   = (const float*)d_in[6];
    const float* Wl1  = (const float*)d_in[7];
    const float* bl1  = (const float*)d_in[8];
    const float* Wl2  = (const float*)d_in[9];
    const float* bl2  = (const float*)d_in[10];

    const int N = in_sizes[0];
    const int E = in_sizes[1] / 2;
    const int G = out_size / 4;
    const int* srcp = ei;
    const int* dstp = ei + E;
    const int NBUCK = (N + 63) >> 6;            // 1563
    const int NCH   = (E + CHUNK - 1) / CHUNK;  // 391

    // Workspace (re-poisoned each call; every buffer fully written before read).
    char* p = (char*)d_ws;
    size_t off = 0;
    int*    hist = (int*)(p + off);    off += align_up((size_t)NCH * NBUCK * 4, 16);
    int*    btot = (int*)(p + off);    off += align_up((size_t)NBUCK * 4, 16);
    int*    babs = (int*)(p + off);    off += align_up((size_t)(NBUCK + 1) * 4, 16);
    float*  dinv = (float*)(p + off);  off += align_up((size_t)N * 4, 16);
    float*  xd   = (float*)(p + off);  off += align_up((size_t)N * 4, 16);
    float2* uv   = (float2*)(p + off); off += align_up((size_t)N * 8, 16);
    float4* abc  = (float4*)(p + off); off += align_up((size_t)N * 16, 16);
    int*    ebuf = (int*)(p + off);    off += align_up((size_t)E * 4, 16);
    (void)ws_size; (void)n_in;

    k_hist    <<<NCH, 256, 0, stream>>>(dstp, hist, E, NBUCK);
    k_cscanA  <<<(NBUCK + 255) / 256, 256, 0, stream>>>(hist, btot, NCH, NBUCK);
    k_cscanB  <<<1, 256, 0, stream>>>(btot, babs, NBUCK, E);
    k_scatter <<<NCH, 256, 0, stream>>>(srcp, dstp, hist, babs, ebuf, E, NBUCK);
    k_degxd   <<<NBUCK, 256, 0, stream>>>(ebuf, babs, x, dinv, xd, N);
    k_t       <<<NBUCK, 256, 0, stream>>>(ebuf, babs, xd, dinv, uv, N);
    k_tda     <<<NBUCK, 256, 0, stream>>>(ebuf, babs, uv, abc, N);
    k_poolhead<<<G, 128, 0, stream>>>(abc, batch, W1, b1, W2, b2,
                                      Wl1, bl1, Wl2, bl2, (float*)d_out, N);
}

// Round 9
// 190.857 us; speedup vs baseline: 2.5871x; 1.2248x over previous
//
#include <hip/hip_runtime.h>
#include <hip/hip_bf16.h>
#include <stdint.h>

// 2-layer GCN + global mean pool + MLP head. N=100000, E=1600000, G=512. fp32.
//
// Fully scalarized: per-edge state is scalar, so the whole GNN reduces to 3
// scalar segment-sums per node over dst-bucket-grouped edges:
//   xd = x*dinv;  t[d] = dinv[d]*(sum xd[src] + xd[d]);  uv = (dinv*t, dinv)
//   (T,D,A)[d] = sum (u_s, v_s, |u_s|) + self;  abc = (dinv/2)*(T,D,A)
//   h2[d,j] = relu(a*alpha_j + b*beta_j + c*gamma_j + b2_j)
//   alpha/beta/gamma fold W1/b1 through W2 (exact for any b1).
//
// Round-8 lesson: k_cscanA (1 thread/bucket, serial over 391 chunks) was a
// 57 us latency bomb at 0.25% occupancy. Now: block-per-bucket parallel scan
// (1563 blocks x 256 threads, 2 chunks/thread) — same math, 250x parallelism.
// Round-7 lesson kept: no cooperative grid.sync; separate launches win.

#define CHUNK   4096
#define MAXBUCK 1600

static inline size_t align_up(size_t x, size_t a){ return (x + a - 1) & ~(a - 1); }

// --- Pass A: per-chunk bucket histogram (LDS) ---
__global__ void __launch_bounds__(256) k_hist(const int* __restrict__ dst,
                                              int* __restrict__ hist, int E, int nbuck){
    __shared__ int h[MAXBUCK];
    for (int i = threadIdx.x; i < nbuck; i += 256) h[i] = 0;
    __syncthreads();
    int base = blockIdx.x * CHUNK;
    int end = min(base + CHUNK, E);
    for (int i = base + threadIdx.x; i < end; i += 256)
        atomicAdd(&h[dst[i] >> 6], 1);
    __syncthreads();
    int* row = hist + (size_t)blockIdx.x * nbuck;
    for (int i = threadIdx.x; i < nbuck; i += 256) row[i] = h[i];
}

// --- Pass B1: block-per-bucket parallel exclusive scan across chunks ---
// (requires nch <= 512; NCH = 391)
__global__ void __launch_bounds__(256) k_cscanA(int* __restrict__ hist,
                                                int* __restrict__ btot,
                                                int nch, int nbuck){
    __shared__ int sh[256];
    int b = blockIdx.x, t = threadIdx.x;
    int c0 = 2 * t, c1 = 2 * t + 1;
    int v0 = (c0 < nch) ? hist[(size_t)c0 * nbuck + b] : 0;
    int v1 = (c1 < nch) ? hist[(size_t)c1 * nbuck + b] : 0;
    sh[t] = v0 + v1; __syncthreads();
    for (int off = 1; off < 256; off <<= 1){
        int xv = (t >= off) ? sh[t - off] : 0;
        __syncthreads();
        if (t >= off) sh[t] += xv;
        __syncthreads();
    }
    int excl = (t == 0) ? 0 : sh[t - 1];
    if (c0 < nch) hist[(size_t)c0 * nbuck + b] = excl;
    if (c1 < nch) hist[(size_t)c1 * nbuck + b] = excl + v0;
    if (t == 255) btot[b] = sh[255];
}

// --- Pass B2: exclusive scan of bucket totals -> bucket base offsets ---
__global__ void k_cscanB(const int* __restrict__ btot, int* __restrict__ babs,
                         int nbuck, int E){
    __shared__ int sh[256];
    int t = threadIdx.x;
    int it = (nbuck + 255) / 256;  // <= 16
    int v[16];
    int sum = 0;
    int base = t * it;
    for (int u = 0; u < it; ++u){
        int idx = base + u;
        v[u] = (idx < nbuck) ? btot[idx] : 0;
        sum += v[u];
    }
    sh[t] = sum; __syncthreads();
    for (int off = 1; off < 256; off <<= 1){
        int xv = (t >= off) ? sh[t - off] : 0;
        __syncthreads();
        if (t >= off) sh[t] += xv;
        __syncthreads();
    }
    int run = (t == 0) ? 0 : sh[t - 1];
    for (int u = 0; u < it; ++u){
        int idx = base + u;
        if (idx < nbuck) babs[idx] = run;
        run += v[u];
    }
    if (t == 0) babs[nbuck] = E;
}

// --- Pass C: ordered scatter into bucket-grouped packed ebuf (LDS cursors) ---
__global__ void __launch_bounds__(256) k_scatter(
        const int* __restrict__ src, const int* __restrict__ dst,
        const int* __restrict__ hist, const int* __restrict__ babs,
        int* __restrict__ ebuf, int E, int nbuck){
    __shared__ int lcur[MAXBUCK];
    const int* rel = hist + (size_t)blockIdx.x * nbuck;
    for (int i = threadIdx.x; i < nbuck; i += 256) lcur[i] = babs[i] + rel[i];
    __syncthreads();
    int base = blockIdx.x * CHUNK;
    int end = min(base + CHUNK, E);
    for (int i = base + threadIdx.x; i < end; i += 256){
        int s = src[i], d = dst[i];
        int slot = atomicAdd(&lcur[d >> 6], 1);
        ebuf[slot] = (s << 6) | (d & 63);
    }
}

// --- degree -> dinv, xd = x*dinv (per bucket, LDS counters) ---
__global__ void __launch_bounds__(256) k_degxd(
        const int* __restrict__ ebuf, const int* __restrict__ babs,
        const float* __restrict__ x, float* __restrict__ dinv,
        float* __restrict__ xd, int N){
    __shared__ int cnt[64];
    int b = blockIdx.x, node0 = b << 6, t = threadIdx.x;
    if (t < 64) cnt[t] = 0;
    __syncthreads();
    int beg = babs[b], end = babs[b + 1];
    for (int i = beg + t; i < end; i += 256)
        atomicAdd(&cnt[ebuf[i] & 63], 1);
    __syncthreads();
    if (t < 64 && node0 + t < N){
        float di = rsqrtf((float)cnt[t] + 1.0f);
        dinv[node0 + t] = di;
        xd[node0 + t] = x[node0 + t] * di;
    }
}

// --- layer-1 scalar t per node; write uv = (dinv*t, dinv) ---
__global__ void __launch_bounds__(256) k_t(
        const int* __restrict__ ebuf, const int* __restrict__ babs,
        const float* __restrict__ xd, const float* __restrict__ dinv,
        float2* __restrict__ uv, int N){
    __shared__ float tl[64], dl[64];
    int b = blockIdx.x, node0 = b << 6, t = threadIdx.x;
    if (t < 64){
        tl[t] = 0.f;
        int n = node0 + t;
        dl[t] = (n < N) ? dinv[n] : 0.f;
    }
    __syncthreads();
    int beg = babs[b], end = babs[b + 1];
    for (int i = beg + t; i < end; i += 256){
        int e = ebuf[i];
        atomicAdd(&tl[e & 63], xd[e >> 6]);
    }
    __syncthreads();
    if (t < 64 && node0 + t < N){
        int n = node0 + t;
        float tv = dl[t] * (tl[t] + xd[n]);
        uv[n] = make_float2(dl[t] * tv, dl[t]);
    }
}

// --- layer-2 scalar sums (T,D,A) per node; write abc = (dinv/2)*(T,D,A) ---
__global__ void __launch_bounds__(256) k_tda(
        const int* __restrict__ ebuf, const int* __restrict__ babs,
        const float2* __restrict__ uv, float4* __restrict__ abc, int N){
    __shared__ float TL[64], DL[64], AL[64], dl2[64];
    int b = blockIdx.x, node0 = b << 6, t = threadIdx.x;
    if (t < 64){
        TL[t] = 0.f; DL[t] = 0.f; AL[t] = 0.f;
        int n = node0 + t;
        dl2[t] = (n < N) ? uv[n].y : 0.f;   // dinv
    }
    __syncthreads();
    int beg = babs[b], end = babs[b + 1];
    for (int i = beg + t; i < end; i += 256){
        int e = ebuf[i];
        float2 s = uv[e >> 6];
        int j = e & 63;
        atomicAdd(&TL[j], s.x);
        atomicAdd(&DL[j], s.y);
        atomicAdd(&AL[j], fabsf(s.x));
    }
    __syncthreads();
    if (t < 64 && node0 + t < N){
        int n = node0 + t;
        float2 s = uv[n];                    // self-loop contribution
        float half_d = 0.5f * dl2[t];
        float T = TL[t] + s.x;
        float D = DL[t] + s.y;
        float A = AL[t] + fabsf(s.x);
        abc[n] = make_float4(half_d * T, half_d * D, half_d * A, 0.f);
    }
}

// --- fused: abg fold + rank-3 relu -> mean pool -> MLP head. Block per graph. ---
#define NS 32
__global__ void __launch_bounds__(128) k_poolhead(
        const float4* __restrict__ abc, const int* __restrict__ batch,
        const float* __restrict__ W1, const float* __restrict__ b1,
        const float* __restrict__ W2, const float* __restrict__ b2,
        const float* __restrict__ Wl1, const float* __restrict__ bl1,
        const float* __restrict__ Wl2, const float* __restrict__ bl2,
        float* __restrict__ out, int N){
    __shared__ float4 st[NS];
    __shared__ float pooled[128];
    __shared__ float h3s[64];
    int g = blockIdx.x;
    int t = threadIdx.x;  // 128
    // fold W1/b1 through W2: alpha/beta/gamma for this thread's column
    float al = 0.f, be = 0.f, ga = 0.f;
    #pragma unroll
    for (int c = 0; c < 64; ++c){
        float w2 = W2[c * 128 + t];
        al = fmaf(W1[c], w2, al);
        be = fmaf(b1[c], w2, be);
        ga = fmaf(fabsf(W1[c]), w2, ga);
    }
    float b2j = b2[t];
    int lo = 0, hi = N;
    while (lo < hi){ int m = (lo + hi) >> 1; if (batch[m] < g) lo = m + 1; else hi = m; }
    int lo2 = lo, hi2 = N;
    while (lo2 < hi2){ int m = (lo2 + hi2) >> 1; if (batch[m] < g + 1) lo2 = m + 1; else hi2 = m; }
    int cnt = lo2 - lo;
    float pool = 0.f;
    for (int base = lo; base < lo2; base += NS){
        int ns = min(NS, lo2 - base);
        if (t < 4 * ns) ((float*)st)[t] = ((const float*)(abc + base))[t];
        __syncthreads();
        for (int u = 0; u < ns; ++u){
            float4 s = st[u];
            float h = fmaf(s.x, al, fmaf(s.y, be, fmaf(s.z, ga, b2j)));
            pool += fmaxf(h, 0.f);
        }
        __syncthreads();
    }
    pooled[t] = pool / (float)(cnt > 0 ? cnt : 1);
    __syncthreads();
    if (t < 64){
        float a = bl1[t];
        #pragma unroll
        for (int k = 0; k < 128; ++k) a = fmaf(pooled[k], Wl1[k * 64 + t], a);
        h3s[t] = fmaxf(a, 0.f);
    }
    __syncthreads();
    if (t < 4){
        float o = bl2[t];
        #pragma unroll
        for (int j = 0; j < 64; ++j) o = fmaf(h3s[j], Wl2[j * 4 + t], o);
        out[g * 4 + t] = o;
    }
}

extern "C" void kernel_launch(void* const* d_in, const int* in_sizes, int n_in,
                              void* d_out, int out_size, void* d_ws, size_t ws_size,
                              hipStream_t stream) {
    const float* x    = (const float*)d_in[0];
    const int*   ei   = (const int*)d_in[1];
    const int*   batch= (const int*)d_in[2];
    const float* W1   = (const float*)d_in[3];
    const float* b1   = (const float*)d_in[4];
    const float* W2   = (const float*)d_in[5];
    const float* b2   = (const float*)d_in[6];
    const float* Wl1  = (const float*)d_in[7];
    const float* bl1  = (const float*)d_in[8];
    const float* Wl2  = (const float*)d_in[9];
    const float* bl2  = (const float*)d_in[10];

    const int N = in_sizes[0];
    const int E = in_sizes[1] / 2;
    const int G = out_size / 4;
    const int* srcp = ei;
    const int* dstp = ei + E;
    const int NBUCK = (N + 63) >> 6;            // 1563
    const int NCH   = (E + CHUNK - 1) / CHUNK;  // 391 (k_cscanA requires <=512)

    // Workspace (re-poisoned each call; every buffer fully written before read).
    char* p = (char*)d_ws;
    size_t off = 0;
    int*    hist = (int*)(p + off);    off += align_up((size_t)NCH * NBUCK * 4, 16);
    int*    btot = (int*)(p + off);    off += align_up((size_t)NBUCK * 4, 16);
    int*    babs = (int*)(p + off);    off += align_up((size_t)(NBUCK + 1) * 4, 16);
    float*  dinv = (float*)(p + off);  off += align_up((size_t)N * 4, 16);
    float*  xd   = (float*)(p + off);  off += align_up((size_t)N * 4, 16);
    float2* uv   = (float2*)(p + off); off += align_up((size_t)N * 8, 16);
    float4* abc  = (float4*)(p + off); off += align_up((size_t)N * 16, 16);
    int*    ebuf = (int*)(p + off);    off += align_up((size_t)E * 4, 16);
    (void)ws_size; (void)n_in;

    k_hist    <<<NCH, 256, 0, stream>>>(dstp, hist, E, NBUCK);
    k_cscanA  <<<NBUCK, 256, 0, stream>>>(hist, btot, NCH, NBUCK);
    k_cscanB  <<<1, 256, 0, stream>>>(btot, babs, NBUCK, E);
    k_scatter <<<NCH, 256, 0, stream>>>(srcp, dstp, hist, babs, ebuf, E, NBUCK);
    k_degxd   <<<NBUCK, 256, 0, stream>>>(ebuf, babs, x, dinv, xd, N);
    k_t       <<<NBUCK, 256, 0, stream>>>(ebuf, babs, xd, dinv, uv, N);
    k_tda     <<<NBUCK, 256, 0, stream>>>(ebuf, babs, uv, abc, N);
    k_poolhead<<<G, 128, 0, stream>>>(abc, batch, W1, b1, W2, b2,
                                      Wl1, bl1, Wl2, bl2, (float*)d_out, N);
}